// Round 1
// baseline (341.528 us; speedup 1.0000x reference)
//
#include <hip/hip_runtime.h>

#define NEMBD 2048
#define ROW4 (NEMBD / 4)    // 512 float4 per row
#define ITERS (ROW4 / 64)   // 8 iterations per token row

// One wave (64 lanes) processes 8 consecutive tokens.
// Lane l accumulates partial dot products for all 8 tokens x 8 experts.
__global__ __launch_bounds__(256, 2) void gate_kernel(
    const float* __restrict__ x, const float* __restrict__ W,
    float* __restrict__ out, float* __restrict__ ws, int ntok, int ngroups)
{
    const int tid  = threadIdx.x;
    const int lane = tid & 63;
    const int wid  = tid >> 6;
    const int nwaves = gridDim.x * 4;
    int gw = blockIdx.x * 4 + wid;

    const float4* X4 = (const float4*)x;
    const float4* W4 = (const float4*)W;
    float* out_p = out;                // [ntok][2] renormalized top-2 probs
    float* out_i = out + 2 * ntok;     // [ntok][2] indices (as float)

    float imp_acc = 0.f, load_acc = 0.f;

    for (int g = gw; g < ngroups; g += nwaves) {
        const int base = g * 8;

        float a[64];
        #pragma unroll
        for (int j = 0; j < 64; ++j) a[j] = 0.f;

        #pragma unroll
        for (int i = 0; i < ITERS; ++i) {
            float4 xv[8];
            #pragma unroll
            for (int k = 0; k < 8; ++k) {
                if (base + k < ntok)   // wave-uniform branch
                    xv[k] = X4[(size_t)(base + k) * ROW4 + i * 64 + lane];
                else
                    xv[k] = make_float4(0.f, 0.f, 0.f, 0.f);
            }
            #pragma unroll
            for (int e = 0; e < 8; ++e) {
                float4 wv = W4[e * ROW4 + i * 64 + lane];
                #pragma unroll
                for (int k = 0; k < 8; ++k) {
                    a[k * 8 + e] += xv[k].x * wv.x + xv[k].y * wv.y
                                  + xv[k].z * wv.z + xv[k].w * wv.w;
                }
            }
        }

        // Distribution reduce: lane l ends with full logit for
        // token (base + (l>>3)), expert (l&7).
        #pragma unroll
        for (int s = 0; s < 6; ++s) {
            const int half = 32 >> s;
            const bool hi = (lane & half) != 0;
            #pragma unroll
            for (int j = 0; j < half; ++j) {
                float send = hi ? a[j] : a[j + half];
                float recv = __shfl_xor(send, half, 64);
                float keep = hi ? a[j + half] : a[j];
                a[j] = keep + recv;
            }
        }
        const float logit = a[0];
        const int e = lane & 7;
        const int k = lane >> 3;
        const bool tvalid = (base + k) < ntok;

        // Softmax across the 8-lane expert group.
        float m = logit;
        #pragma unroll
        for (int mm = 1; mm <= 4; mm <<= 1) m = fmaxf(m, __shfl_xor(m, mm, 64));
        float p = __expf(logit - m);
        float ssum = p;
        #pragma unroll
        for (int mm = 1; mm <= 4; mm <<= 1) ssum += __shfl_xor(ssum, mm, 64);
        const float prob = p / ssum;

        // Top-2 butterfly merge (lower index wins on ties, matching
        // jax.lax.top_k / argmax first-occurrence semantics).
        float v1 = prob, v2 = -1.f;
        int   i1 = e,    i2 = -1;
        #pragma unroll
        for (int mm = 1; mm <= 4; mm <<= 1) {
            float b1 = __shfl_xor(v1, mm, 64);
            float b2 = __shfl_xor(v2, mm, 64);
            int  bi1 = __shfl_xor(i1, mm, 64);
            int  bi2 = __shfl_xor(i2, mm, 64);
            bool aw = (v1 > b1) || (v1 == b1 && i1 < bi1);
            float w1 = aw ? v1 : b1;  int wi1 = aw ? i1 : bi1;
            float l1 = aw ? b1 : v1;  int li1 = aw ? bi1 : i1;
            float w2 = aw ? v2 : b2;  int wi2 = aw ? i2 : bi2;
            bool sw = (l1 > w2) || (l1 == w2 && li1 < wi2);
            v1 = w1; i1 = wi1;
            v2 = sw ? l1 : w2;  i2 = sw ? li1 : wi2;
        }

        if (e == 0 && tvalid) {
            const int t = base + k;
            const float denom = v1 + v2;
            out_p[2 * t]     = v1 / denom;
            out_p[2 * t + 1] = v2 / denom;
            out_i[2 * t]     = (float)i1;
            out_i[2 * t + 1] = (float)i2;
        }

        // Aux-loss stats: importance (sum of probs) and load (one-hot top1),
        // reduced across the token dimension (lane bits 3..5).
        float pc = tvalid ? prob : 0.f;
        float oc = (tvalid && e == i1) ? 1.f : 0.f;
        #pragma unroll
        for (int mm = 8; mm <= 32; mm <<= 1) {
            pc += __shfl_xor(pc, mm, 64);
            oc += __shfl_xor(oc, mm, 64);
        }
        imp_acc  += pc;   // lane l holds sum for expert l&7; lanes 0..7 used
        load_acc += oc;
    }

    __shared__ float part[4][16];
    if (lane < 8) {
        part[wid][lane]     = imp_acc;
        part[wid][lane + 8] = load_acc;
    }
    __syncthreads();
    if (tid < 16) {
        ws[blockIdx.x * 16 + tid] =
            part[0][tid] + part[1][tid] + part[2][tid] + part[3][tid];
    }
}

__global__ void finalize_kernel(const float* __restrict__ ws,
                                float* __restrict__ out, int nblk, int ntok)
{
    __shared__ float s[16][16];
    __shared__ float tot[16];
    const int t = threadIdx.x;
    const int slot = t & 15, chunk = t >> 4;
    float p = 0.f;
    for (int b = chunk; b < nblk; b += 16) p += ws[b * 16 + slot];
    s[chunk][slot] = p;
    __syncthreads();
    if (t < 16) {
        float v = 0.f;
        #pragma unroll
        for (int c = 0; c < 16; ++c) v += s[c][t];
        tot[t] = v;
    }
    __syncthreads();
    if (t == 0) {
        const float inv = 1.f / (float)ntok;
        float aux = 0.f;
        #pragma unroll
        for (int e = 0; e < 8; ++e)
            aux += (tot[e] * inv) * (tot[8 + e] * inv);
        out[4 * ntok] = 8.f * aux * 0.01f;
    }
}

extern "C" void kernel_launch(void* const* d_in, const int* in_sizes, int n_in,
                              void* d_out, int out_size, void* d_ws, size_t ws_size,
                              hipStream_t stream)
{
    const float* x = (const float*)d_in[0];
    const float* W = (const float*)d_in[1];
    const int ntok    = in_sizes[0] / NEMBD;   // 16384
    const int ngroups = (ntok + 7) / 8;        // 2048 wave-groups
    const int nblocks = (ngroups + 3) / 4;     // 512 blocks x 4 waves

    gate_kernel<<<nblocks, 256, 0, stream>>>(
        x, W, (float*)d_out, (float*)d_ws, ntok, ngroups);
    finalize_kernel<<<1, 256, 0, stream>>>(
        (const float*)d_ws, (float*)d_out, nblocks, ntok);
}

// Round 2
// 238.791 us; speedup vs baseline: 1.4302x; 1.4302x over previous
//
#include <hip/hip_runtime.h>

#define NEMBD 2048
#define ROW4 (NEMBD / 4)      // 512 float4 per row
#define HITERS (ROW4 / 32)    // 16 iterations per token row, 32 lanes/half

// One wave = 8 tokens. Lanes split into two 32-lane halves; half h owns
// tokens base+4h .. base+4h+3. Each lane: 32 accumulators (4 tok x 8 exp).
__global__ __launch_bounds__(256) void gate_kernel(
    const float* __restrict__ x, const float* __restrict__ W,
    float* __restrict__ out, float* __restrict__ ws, int ntok, int ngroups)
{
    const int tid  = threadIdx.x;
    const int lane = tid & 63;
    const int wid  = tid >> 6;
    const int half = lane >> 5;     // 0 or 1
    const int j    = lane & 31;     // lane within half
    const int nwaves = gridDim.x * 4;
    int gw = blockIdx.x * 4 + wid;

    const float4* X4 = (const float4*)x;
    const float4* W4 = (const float4*)W;
    float* out_p = out;             // [ntok][2] renormalized top-2 probs
    float* out_i = out + 2 * ntok;  // [ntok][2] indices (as float)

    float imp_acc = 0.f, load_acc = 0.f;

    for (int g = gw; g < ngroups; g += nwaves) {
        const int base = g * 8;
        const int tb = base + 4 * half;   // this half's first token

        float a[32];
        #pragma unroll
        for (int q = 0; q < 32; ++q) a[q] = 0.f;

        for (int i = 0; i < HITERS; ++i) {
            const int col = i * 32 + j;
            float4 xv[4];
            #pragma unroll
            for (int k = 0; k < 4; ++k)
                xv[k] = X4[(tb + k) * ROW4 + col];
            #pragma unroll
            for (int e = 0; e < 8; ++e) {
                float4 wv = W4[e * ROW4 + col];
                #pragma unroll
                for (int k = 0; k < 4; ++k) {
                    a[k * 8 + e] += xv[k].x * wv.x + xv[k].y * wv.y
                                  + xv[k].z * wv.z + xv[k].w * wv.w;
                }
            }
        }

        // Distribution reduce within each 32-lane half: after 5 steps,
        // lane l holds the full logit for accumulator index (l&31), i.e.
        // token base + (l>>3), expert (l&7).
        #pragma unroll
        for (int s = 0; s < 5; ++s) {
            const int hm = 16 >> s;
            const bool hi = (lane & hm) != 0;
            #pragma unroll
            for (int q = 0; q < 16; ++q) {
                if (q < hm) {
                    float send = hi ? a[q] : a[q + hm];
                    float recv = __shfl_xor(send, hm, 64);
                    float keep = hi ? a[q + hm] : a[q];
                    a[q] = keep + recv;
                }
            }
        }
        const float logit = a[0];
        const int e = lane & 7;
        const int k = lane >> 3;
        const bool tvalid = (base + k) < ntok;

        // Softmax across the 8-lane expert group.
        float m = logit;
        #pragma unroll
        for (int mm = 1; mm <= 4; mm <<= 1) m = fmaxf(m, __shfl_xor(m, mm, 64));
        float p = __expf(logit - m);
        float ssum = p;
        #pragma unroll
        for (int mm = 1; mm <= 4; mm <<= 1) ssum += __shfl_xor(ssum, mm, 64);
        const float prob = p / ssum;

        // Top-2 butterfly merge (lower index wins ties — matches
        // jax.lax.top_k / argmax first-occurrence semantics).
        float v1 = prob, v2 = -1.f;
        int   i1 = e,    i2 = -1;
        #pragma unroll
        for (int mm = 1; mm <= 4; mm <<= 1) {
            float b1 = __shfl_xor(v1, mm, 64);
            float b2 = __shfl_xor(v2, mm, 64);
            int  bi1 = __shfl_xor(i1, mm, 64);
            int  bi2 = __shfl_xor(i2, mm, 64);
            bool aw = (v1 > b1) || (v1 == b1 && i1 < bi1);
            float w1 = aw ? v1 : b1;  int wi1 = aw ? i1 : bi1;
            float l1 = aw ? b1 : v1;  int li1 = aw ? bi1 : i1;
            float w2 = aw ? v2 : b2;  int wi2 = aw ? i2 : bi2;
            bool sw = (l1 > w2) || (l1 == w2 && li1 < wi2);
            v1 = w1; i1 = wi1;
            v2 = sw ? l1 : w2;  i2 = sw ? li1 : wi2;
        }

        if (e == 0 && tvalid) {
            const int t = base + k;
            const float denom = v1 + v2;
            out_p[2 * t]     = v1 / denom;
            out_p[2 * t + 1] = v2 / denom;
            out_i[2 * t]     = (float)i1;
            out_i[2 * t + 1] = (float)i2;
        }

        // Aux-loss partials: reduce prob and one-hot(top1) across the
        // token dimension (lane bits 3..5). Lane l accumulates expert l&7.
        float pc = tvalid ? prob : 0.f;
        float oc = (tvalid && e == i1) ? 1.f : 0.f;
        #pragma unroll
        for (int mm = 8; mm <= 32; mm <<= 1) {
            pc += __shfl_xor(pc, mm, 64);
            oc += __shfl_xor(oc, mm, 64);
        }
        imp_acc  += pc;
        load_acc += oc;
    }

    __shared__ float part[4][16];
    if (lane < 8) {
        part[wid][lane]     = imp_acc;
        part[wid][lane + 8] = load_acc;
    }
    __syncthreads();
    if (tid < 16) {
        ws[blockIdx.x * 16 + tid] =
            part[0][tid] + part[1][tid] + part[2][tid] + part[3][tid];
    }
}

__global__ void finalize_kernel(const float* __restrict__ ws,
                                float* __restrict__ out, int nblk, int ntok)
{
    __shared__ float s[16][16];
    __shared__ float tot[16];
    const int t = threadIdx.x;
    const int slot = t & 15, chunk = t >> 4;
    float p = 0.f;
    for (int b = chunk; b < nblk; b += 16) p += ws[b * 16 + slot];
    s[chunk][slot] = p;
    __syncthreads();
    if (t < 16) {
        float v = 0.f;
        #pragma unroll
        for (int c = 0; c < 16; ++c) v += s[c][t];
        tot[t] = v;
    }
    __syncthreads();
    if (t == 0) {
        const float inv = 1.f / (float)ntok;
        float aux = 0.f;
        #pragma unroll
        for (int e = 0; e < 8; ++e)
            aux += (tot[e] * inv) * (tot[8 + e] * inv);
        out[4 * ntok] = 8.f * aux * 0.01f;
    }
}

extern "C" void kernel_launch(void* const* d_in, const int* in_sizes, int n_in,
                              void* d_out, int out_size, void* d_ws, size_t ws_size,
                              hipStream_t stream)
{
    const float* x = (const float*)d_in[0];
    const float* W = (const float*)d_in[1];
    const int ntok    = in_sizes[0] / NEMBD;   // 16384
    const int ngroups = (ntok + 7) / 8;        // 2048 wave-groups
    const int nblocks = (ngroups + 3) / 4;     // 512 blocks x 4 waves

    gate_kernel<<<nblocks, 256, 0, stream>>>(
        x, W, (float*)d_out, (float*)d_ws, ntok, ngroups);
    finalize_kernel<<<1, 256, 0, stream>>>(
        (const float*)d_ws, (float*)d_out, nblocks, ntok);
}

// Round 4
// 214.952 us; speedup vs baseline: 1.5889x; 1.1109x over previous
//
#include <hip/hip_runtime.h>

#define NEMBD 2048
#define ROW4 (NEMBD / 4)    // 512 float4 per token row
#define CHUNKS (ROW4 / 64)  // 8 full-wave column chunks per row

// One wave = 2 consecutive tokens; 16 accumulators/lane (2 tok x 8 exp).
// Block = 4 waves = 8 tokens. Grid = ntok/8 blocks -> 8 waves/SIMD queued.
__global__ __launch_bounds__(256) void gate_kernel(
    const float* __restrict__ x, const float* __restrict__ W,
    float* __restrict__ out, float* __restrict__ ws, int ntok)
{
    const int tid  = threadIdx.x;
    const int lane = tid & 63;
    const int wid  = tid >> 6;

    const int t0 = blockIdx.x * 8 + wid * 2;   // this wave's first token
    const bool va0 = t0 < ntok, va1 = (t0 + 1) < ntok;

    const float4* X4 = (const float4*)x;
    const float4* W4 = (const float4*)W;
    float* out_p = out;             // [ntok][2] renormalized top-2 probs
    float* out_i = out + 2 * ntok;  // [ntok][2] indices (as float)

    float a[16];
    #pragma unroll
    for (int q = 0; q < 16; ++q) a[q] = 0.f;

    const float4 z4 = make_float4(0.f, 0.f, 0.f, 0.f);

    #pragma unroll 2
    for (int i = 0; i < CHUNKS; ++i) {
        const int col = i * 64 + lane;
        float4 x0 = va0 ? X4[(size_t)t0 * ROW4 + col] : z4;
        float4 x1 = va1 ? X4[(size_t)(t0 + 1) * ROW4 + col] : z4;
        #pragma unroll
        for (int e = 0; e < 8; ++e) {
            float4 wv = W4[e * ROW4 + col];
            a[e]     += x0.x * wv.x + x0.y * wv.y + x0.z * wv.z + x0.w * wv.w;
            a[8 + e] += x1.x * wv.x + x1.y * wv.y + x1.z * wv.z + x1.w * wv.w;
        }
    }

    // Reduce across lanes. Two pure butterfly steps collapse the 4 lanes
    // sharing (lane mod 16); four split steps distribute so lane l holds
    // the full logit for accumulator index (l & 15):
    //   token t0 + ((l>>3)&1), expert (l&7).  (16-lane groups replicate.)
    #pragma unroll
    for (int q = 0; q < 16; ++q) a[q] += __shfl_xor(a[q], 32, 64);
    #pragma unroll
    for (int q = 0; q < 16; ++q) a[q] += __shfl_xor(a[q], 16, 64);
    #pragma unroll
    for (int s = 0; s < 4; ++s) {
        const int hm = 8 >> s;
        const bool hi = (lane & hm) != 0;
        #pragma unroll
        for (int q = 0; q < 8; ++q) {
            if (q < hm) {
                float send = hi ? a[q] : a[q + hm];
                float recv = __shfl_xor(send, hm, 64);
                float keep = hi ? a[q + hm] : a[q];
                a[q] = keep + recv;
            }
        }
    }
    const float logit = a[0];
    const int e = lane & 7;
    const int k = (lane >> 3) & 1;
    const bool tvalid = (t0 + k) < ntok;

    // Softmax across the 8-lane expert group.
    float m = logit;
    #pragma unroll
    for (int mm = 1; mm <= 4; mm <<= 1) m = fmaxf(m, __shfl_xor(m, mm, 64));
    float p = __expf(logit - m);
    float ssum = p;
    #pragma unroll
    for (int mm = 1; mm <= 4; mm <<= 1) ssum += __shfl_xor(ssum, mm, 64);
    const float prob = p / ssum;

    // Top-2 butterfly merge (lower index wins ties — matches jax.lax.top_k
    // / argmax first-occurrence semantics).
    float v1 = prob, v2 = -1.f;
    int   i1 = e,    i2 = -1;
    #pragma unroll
    for (int mm = 1; mm <= 4; mm <<= 1) {
        float b1 = __shfl_xor(v1, mm, 64);
        float b2 = __shfl_xor(v2, mm, 64);
        int  bi1 = __shfl_xor(i1, mm, 64);
        int  bi2 = __shfl_xor(i2, mm, 64);
        bool aw = (v1 > b1) || (v1 == b1 && i1 < bi1);
        float w1 = aw ? v1 : b1;  int wi1 = aw ? i1 : bi1;
        float l1 = aw ? b1 : v1;  int li1 = aw ? bi1 : i1;
        float w2 = aw ? v2 : b2;  int wi2 = aw ? i2 : bi2;
        bool sw = (l1 > w2) || (l1 == w2 && li1 < wi2);
        v1 = w1; i1 = wi1;
        v2 = sw ? l1 : w2;  i2 = sw ? li1 : wi2;
    }

    if (e == 0 && lane < 16 && tvalid) {
        const int t = t0 + k;
        const float denom = v1 + v2;
        out_p[2 * t]     = v1 / denom;
        out_p[2 * t + 1] = v2 / denom;
        out_i[2 * t]     = (float)i1;
        out_i[2 * t + 1] = (float)i2;
    }

    // Aux-loss partials. Sum over the wave's 2 tokens (xor 8); lanes 0-7
    // then hold per-expert sums (16-lane groups replicate; use lanes 0-7).
    float pc = tvalid ? prob : 0.f;
    float oc = (tvalid && e == i1) ? 1.f : 0.f;
    pc += __shfl_xor(pc, 8, 64);
    oc += __shfl_xor(oc, 8, 64);

    __shared__ float part[4][16];
    if (lane < 8) {
        part[wid][lane]     = pc;
        part[wid][lane + 8] = oc;
    }
    __syncthreads();
    if (tid < 16) {
        atomicAdd(&ws[tid],
                  part[0][tid] + part[1][tid] + part[2][tid] + part[3][tid]);
    }
}

__global__ void finalize_kernel(const float* __restrict__ ws,
                                float* __restrict__ out, int ntok)
{
    if (threadIdx.x == 0) {
        const float inv = 1.f / (float)ntok;
        float aux = 0.f;
        #pragma unroll
        for (int e = 0; e < 8; ++e)
            aux += (ws[e] * inv) * (ws[8 + e] * inv);
        out[4 * ntok] = 8.f * aux * 0.01f;
    }
}

extern "C" void kernel_launch(void* const* d_in, const int* in_sizes, int n_in,
                              void* d_out, int out_size, void* d_ws, size_t ws_size,
                              hipStream_t stream)
{
    const float* x = (const float*)d_in[0];
    const float* W = (const float*)d_in[1];
    const int ntok    = in_sizes[0] / NEMBD;    // 16384
    const int nblocks = (ntok + 7) / 8;         // 2048 blocks x 4 waves

    hipMemsetAsync(d_ws, 0, 16 * sizeof(float), stream);
    gate_kernel<<<nblocks, 256, 0, stream>>>(
        x, W, (float*)d_out, (float*)d_ws, ntok);
    finalize_kernel<<<1, 64, 0, stream>>>(
        (const float*)d_ws, (float*)d_out, ntok);
}

// Round 7
// 211.402 us; speedup vs baseline: 1.6155x; 1.0168x over previous
//
#include <hip/hip_runtime.h>

#define NEMBD 2048
#define ROW4 (NEMBD / 4)    // 512 float4 per token row
#define CHUNKS (ROW4 / 64)  // 8 full-wave column chunks per row
#define NEXP 8
#define W4N (NEXP * ROW4)   // 4096 float4 = 64 KB

// Block = 1024 threads = 16 waves. W (64 KB) staged once per block in LDS.
// One wave = 2 consecutive tokens; 16 accumulators/lane (2 tok x 8 exp).
// Grid = ntok/32 = 512 blocks -> 2 blocks/CU (LDS-limited), 8 waves/SIMD.
__global__ __launch_bounds__(1024) void gate_kernel(
    const float* __restrict__ x, const float* __restrict__ W,
    float* __restrict__ out, float* __restrict__ ws, int ntok)
{
    __shared__ float4 Wl[W4N];          // exactly 64 KB

    const int tid  = threadIdx.x;
    const int lane = tid & 63;
    const int wid  = tid >> 6;          // 0..15

    const float4* X4 = (const float4*)x;
    const float4* W4 = (const float4*)W;

    // Stage W into LDS: 4 coalesced float4 loads per thread.
    #pragma unroll
    for (int k = 0; k < 4; ++k)
        Wl[tid + k * 1024] = W4[tid + k * 1024];
    __syncthreads();

    const int t0 = blockIdx.x * 32 + wid * 2;   // this wave's first token
    const bool va0 = t0 < ntok, va1 = (t0 + 1) < ntok;

    float* out_p = out;             // [ntok][2] renormalized top-2 probs
    float* out_i = out + 2 * ntok;  // [ntok][2] indices (as float)

    float a[16];
    #pragma unroll
    for (int q = 0; q < 16; ++q) a[q] = 0.f;

    const float4 z4 = make_float4(0.f, 0.f, 0.f, 0.f);

    #pragma unroll 2
    for (int i = 0; i < CHUNKS; ++i) {
        const int col = i * 64 + lane;
        float4 x0 = va0 ? X4[(size_t)t0 * ROW4 + col] : z4;
        float4 x1 = va1 ? X4[(size_t)(t0 + 1) * ROW4 + col] : z4;
        #pragma unroll
        for (int e = 0; e < 8; ++e) {
            float4 wv = Wl[e * ROW4 + col];
            a[e]     += x0.x * wv.x + x0.y * wv.y + x0.z * wv.z + x0.w * wv.w;
            a[8 + e] += x1.x * wv.x + x1.y * wv.y + x1.z * wv.z + x1.w * wv.w;
        }
    }

    // Reduce across lanes. Two pure butterfly steps collapse the 4 lanes
    // sharing (lane mod 16); four split steps distribute so lane l holds
    // the full logit for accumulator index (l & 15):
    //   token t0 + ((l>>3)&1), expert (l&7).  (16-lane groups replicate.)
    #pragma unroll
    for (int q = 0; q < 16; ++q) a[q] += __shfl_xor(a[q], 32, 64);
    #pragma unroll
    for (int q = 0; q < 16; ++q) a[q] += __shfl_xor(a[q], 16, 64);
    #pragma unroll
    for (int s = 0; s < 4; ++s) {
        const int hm = 8 >> s;
        const bool hi = (lane & hm) != 0;
        #pragma unroll
        for (int q = 0; q < 8; ++q) {
            if (q < hm) {
                float send = hi ? a[q] : a[q + hm];
                float recv = __shfl_xor(send, hm, 64);
                float keep = hi ? a[q + hm] : a[q];
                a[q] = keep + recv;
            }
        }
    }
    const float logit = a[0];
    const int e = lane & 7;
    const int k = (lane >> 3) & 1;
    const bool tvalid = (t0 + k) < ntok;

    // Softmax across the 8-lane expert group.
    float m = logit;
    #pragma unroll
    for (int mm = 1; mm <= 4; mm <<= 1) m = fmaxf(m, __shfl_xor(m, mm, 64));
    float p = __expf(logit - m);
    float ssum = p;
    #pragma unroll
    for (int mm = 1; mm <= 4; mm <<= 1) ssum += __shfl_xor(ssum, mm, 64);
    const float prob = p / ssum;

    // Top-2 butterfly merge (lower index wins ties — matches jax.lax.top_k
    // / argmax first-occurrence semantics).
    float v1 = prob, v2 = -1.f;
    int   i1 = e,    i2 = -1;
    #pragma unroll
    for (int mm = 1; mm <= 4; mm <<= 1) {
        float b1 = __shfl_xor(v1, mm, 64);
        float b2 = __shfl_xor(v2, mm, 64);
        int  bi1 = __shfl_xor(i1, mm, 64);
        int  bi2 = __shfl_xor(i2, mm, 64);
        bool aw = (v1 > b1) || (v1 == b1 && i1 < bi1);
        float w1 = aw ? v1 : b1;  int wi1 = aw ? i1 : bi1;
        float l1 = aw ? b1 : v1;  int li1 = aw ? bi1 : i1;
        float w2 = aw ? v2 : b2;  int wi2 = aw ? i2 : bi2;
        bool sw = (l1 > w2) || (l1 == w2 && li1 < wi2);
        v1 = w1; i1 = wi1;
        v2 = sw ? l1 : w2;  i2 = sw ? li1 : wi2;
    }

    if (e == 0 && lane < 16 && tvalid) {
        const int t = t0 + k;
        const float denom = v1 + v2;
        out_p[2 * t]     = v1 / denom;
        out_p[2 * t + 1] = v2 / denom;
        out_i[2 * t]     = (float)i1;
        out_i[2 * t + 1] = (float)i2;
    }

    // Aux-loss partials. Sum over the wave's 2 tokens (xor 8): lanes l and
    // l^8 both end with the per-expert (l&7) sums.
    float pc = tvalid ? prob : 0.f;
    float oc = (tvalid && e == i1) ? 1.f : 0.f;
    pc += __shfl_xor(pc, 8, 64);
    oc += __shfl_xor(oc, 8, 64);

    // Reuse the W LDS region for per-wave partials (W reads are all done).
    float* part = (float*)Wl;           // [16 waves][16]
    __syncthreads();                    // last W read before overwrite
    if (lane < 8)       part[wid * 16 + lane] = pc;        // imp[e]
    else if (lane < 16) part[wid * 16 + lane] = oc;        // load[e] at +8
    __syncthreads();
    if (tid < 16) {
        float v = 0.f;
        #pragma unroll
        for (int w = 0; w < 16; ++w) v += part[w * 16 + tid];
        ws[blockIdx.x * 16 + tid] = v;
    }
}

__global__ void finalize_kernel(const float* __restrict__ ws,
                                float* __restrict__ out, int nblk, int ntok)
{
    __shared__ float s[16][16];
    __shared__ float tot[16];
    const int t = threadIdx.x;
    const int slot = t & 15, chunk = t >> 4;
    float p = 0.f;
    for (int b = chunk; b < nblk; b += 16) p += ws[b * 16 + slot];
    s[chunk][slot] = p;
    __syncthreads();
    if (t < 16) {
        float v = 0.f;
        #pragma unroll
        for (int c = 0; c < 16; ++c) v += s[c][t];
        tot[t] = v;
    }
    __syncthreads();
    if (t == 0) {
        const float inv = 1.f / (float)ntok;
        float aux = 0.f;
        #pragma unroll
        for (int e = 0; e < 8; ++e)
            aux += (tot[e] * inv) * (tot[8 + e] * inv);
        out[4 * ntok] = 8.f * aux * 0.01f;
    }
}

extern "C" void kernel_launch(void* const* d_in, const int* in_sizes, int n_in,
                              void* d_out, int out_size, void* d_ws, size_t ws_size,
                              hipStream_t stream)
{
    const float* x = (const float*)d_in[0];
    const float* W = (const float*)d_in[1];
    const int ntok    = in_sizes[0] / NEMBD;    // 16384
    const int nblocks = (ntok + 31) / 32;       // 512 blocks x 16 waves

    gate_kernel<<<nblocks, 1024, 0, stream>>>(
        x, W, (float*)d_out, (float*)d_ws, ntok);
    finalize_kernel<<<1, 256, 0, stream>>>(
        (const float*)d_ws, (float*)d_out, nblocks, ntok);
}